// Round 1
// baseline (3462.474 us; speedup 1.0000x reference)
//
#include <hip/hip_runtime.h>

#define BB 2
#define HH 128
#define WW 256
#define CC 768
#define NB 8
#define BS 96
#define WKEPT 65
#define NPTS (BB*HH*WKEPT)        // 16640 kept (b,h,w') points
#define NTOT ((size_t)BB*HH*WW*CC) // 50331648
#define TWOPI 6.283185307179586f

// ---------------------------------------------------------------------------
// K0: precombine weights.
// w1p=0.5(w1[0]+w1[1]), w1m=0.5(w1[0]-w1[1])
// layer2 collapsed:  s = o1k*WK + o1nk*WNK + BEFF
//   WK  = w2p + w2p@w2m
//   WNK = w2p + w2m + w2m@w2m
//   BEFF= b2[0] + b2[1] + b2[0]@w2m
// ---------------------------------------------------------------------------
__global__ __launch_bounds__(256) void k_weights(
    const float* __restrict__ w1, const float* __restrict__ w2,
    const float* __restrict__ b2,
    float* __restrict__ W1P, float* __restrict__ W1M,
    float* __restrict__ WKm, float* __restrict__ WNK, float* __restrict__ BEFF)
{
    const int n = blockIdx.x;
    const int tid = threadIdx.x;
    __shared__ float m_s[BS*BS];   // w2m, 36.9 KB

    const float* w2a = w2 + (size_t)(0*NB + n)*BS*BS;
    const float* w2b = w2 + (size_t)(1*NB + n)*BS*BS;
    for (int idx = tid; idx < BS*BS; idx += 256)
        m_s[idx] = 0.5f*(w2a[idx] - w2b[idx]);

    const float* w1a = w1 + (size_t)(0*NB + n)*BS*BS;
    const float* w1b = w1 + (size_t)(1*NB + n)*BS*BS;
    for (int idx = tid; idx < BS*BS; idx += 256) {
        float t0 = w1a[idx], t1 = w1b[idx];
        W1P[n*BS*BS + idx] = 0.5f*(t0 + t1);
        W1M[n*BS*BS + idx] = 0.5f*(t0 - t1);
    }
    __syncthreads();

    for (int idx = tid; idx < BS*BS; idx += 256) {
        int i = idx / BS, o = idx - i*BS;
        float p_io = 0.5f*(w2a[idx] + w2b[idx]);
        float m_io = m_s[idx];
        float accK = 0.f, accN = 0.f;
        for (int j = 0; j < BS; ++j) {
            float p_ij = 0.5f*(w2a[i*BS + j] + w2b[i*BS + j]);
            float mjo  = m_s[j*BS + o];
            accK += p_ij * mjo;
            accN += m_s[i*BS + j] * mjo;
        }
        WKm[n*BS*BS + idx] = p_io + accK;
        WNK[n*BS*BS + idx] = p_io + m_io + accN;
    }
    if (tid < BS) {
        const float* b2a = b2 + (0*NB + n)*BS;
        const float* b2b = b2 + (1*NB + n)*BS;
        float acc = b2a[tid] + b2b[tid];
        for (int j = 0; j < BS; ++j) acc += b2a[j] * m_s[j*BS + tid];
        BEFF[n*BS + tid] = acc;
    }
}

// ---------------------------------------------------------------------------
// P1: forward W-axis pruned DFT (256 -> 65 outputs), real input.
// grid (27 = 3 ctiles * 9 wgroups, 128 h, 2 b), 256 thr. out[b][h][w'][c] cplx
// ---------------------------------------------------------------------------
__global__ __launch_bounds__(256) void k_p1(
    const float* __restrict__ x, float2* __restrict__ out)
{
    const int tid = threadIdx.x;
    const int ct = blockIdx.x % 3;
    const int wg = blockIdx.x / 3;        // 0..8
    const int h = blockIdx.y, b = blockIdx.z;
    const int c = ct*256 + tid;
    const int wpb = wg*8;

    __shared__ float2 tw[256][8];         // 16 KB: (cos,sin) of 2*pi*w*(wpb+j)/256
    for (int idx = tid; idx < 2048; idx += 256) {
        int w = idx >> 3, j = idx & 7;
        int ai = (w * (wpb + j)) & 255;
        float sn, cs; sincosf(TWOPI * (float)ai / 256.0f, &sn, &cs);
        tw[w][j] = make_float2(cs, sn);
    }
    __syncthreads();

    float re[8] = {0,0,0,0,0,0,0,0}, im[8] = {0,0,0,0,0,0,0,0};
    const float* xrow = x + (size_t)(b*HH + h) * WW * CC + c;
    for (int w = 0; w < 256; ++w) {
        float xv = xrow[(size_t)w * CC];
        const float4* t4 = (const float4*)(&tw[w][0]);
        #pragma unroll
        for (int jj = 0; jj < 4; ++jj) {
            float4 q = t4[jj];            // (c0,s0,c1,s1)
            re[2*jj]   += xv * q.x;  im[2*jj]   -= xv * q.y;
            re[2*jj+1] += xv * q.z;  im[2*jj+1] -= xv * q.w;
        }
    }
    #pragma unroll
    for (int j = 0; j < 8; ++j) {
        int wp = wpb + j;
        if (wp < WKEPT)
            out[(size_t)((b*HH + h)*WKEPT + wp) * CC + c] = make_float2(re[j], im[j]);
    }
}

// ---------------------------------------------------------------------------
// P2/P6: C-axis full 768-pt DFT per line, Cooley-Tukey 3x256 with per-thread
// twiddle recurrence. grid (65, 128, 2), 256 thr. layout [line][c] cplx.
// ---------------------------------------------------------------------------
__global__ __launch_bounds__(256) void k_cdft(
    const float2* __restrict__ in, float2* __restrict__ out)
{
    const int tid = threadIdx.x;          // r in 0..255
    const size_t line = (size_t)(blockIdx.z * HH + blockIdx.y) * WKEPT + blockIdx.x;
    const float2* zin = in + line * CC;
    __shared__ float2 zs[CC];             // 6 KB
    for (int idx = tid; idx < CC; idx += 256) zs[idx] = zin[idx];
    __syncthreads();

    float sn, cs; sincosf(TWOPI * (float)tid / 256.0f, &sn, &cs);
    const float str = cs, sti = -sn;      // step = e^{-2pi i r/256}
    float t_r = 1.f, t_i = 0.f;
    float s0r=0,s0i=0,s1r=0,s1i=0,s2r=0,s2i=0;
    #pragma unroll 4
    for (int m = 0; m < 256; ++m) {
        float2 z0 = zs[3*m], z1 = zs[3*m+1], z2 = zs[3*m+2];
        s0r += z0.x*t_r - z0.y*t_i;  s0i += z0.x*t_i + z0.y*t_r;
        s1r += z1.x*t_r - z1.y*t_i;  s1i += z1.x*t_i + z1.y*t_r;
        s2r += z2.x*t_r - z2.y*t_i;  s2i += z2.x*t_i + z2.y*t_r;
        float nr = t_r*str - t_i*sti; t_i = t_r*sti + t_i*str; t_r = nr;
    }
    float2* o = out + line * CC;
    #pragma unroll
    for (int q = 0; q < 3; ++q) {
        int cp = q*256 + tid;
        float sq, cq; sincosf(TWOPI * (float)cp / 768.0f, &sq, &cq);
        float w_r = cq, w_i = -sq;                       // e^{-2pi i cp/768}
        float w2r = w_r*w_r - w_i*w_i, w2i = 2.f*w_r*w_i;
        float fr = s0r + w_r*s1r - w_i*s1i + w2r*s2r - w2i*s2i;
        float fi = s0i + w_r*s1i + w_i*s1r + w2r*s2i + w2i*s2r;
        o[cp] = make_float2(fr, fi);
    }
}

// ---------------------------------------------------------------------------
// P3: H-axis 128-pt DFT + B-axis butterfly on complex input, then a=Re+Im.
// grid (48 ctiles of 16, 65 w'), 256 thr.
// ---------------------------------------------------------------------------
#define CT3 16
__global__ __launch_bounds__(256) void k_hb_c2a(
    const float2* __restrict__ in, float* __restrict__ aout)
{
    const int tid = threadIdx.x;
    const int wp = blockIdx.y;
    const int c0 = blockIdx.x * CT3;
    __shared__ float2 us[HH][CT3];  // 16 KB
    __shared__ float2 vs[HH][CT3];  // 16 KB
    __shared__ float2 rt[HH];       // (cos,sin) of 2*pi*j/128
    if (tid < HH) { float sn, cse; sincosf(TWOPI*(float)tid/128.f, &sn, &cse); rt[tid] = make_float2(cse, sn); }
    for (int idx = tid; idx < HH*CT3; idx += 256) {
        int h = idx / CT3, cl = idx - (idx / CT3)*CT3;
        float2 z0 = in[(size_t)((0*HH + h)*WKEPT + wp)*CC + c0 + cl];
        float2 z1 = in[(size_t)((1*HH + h)*WKEPT + wp)*CC + c0 + cl];
        us[h][cl] = make_float2(z0.x+z1.x, z0.y+z1.y);
        vs[h][cl] = make_float2(z0.x-z1.x, z0.y-z1.y);
    }
    __syncthreads();
    const int cl = tid & 15, hg = tid >> 4;   // hg 0..15, h' = k*16+hg
    float ur[8]={0,0,0,0,0,0,0,0}, ui[8]={0,0,0,0,0,0,0,0};
    float vr[8]={0,0,0,0,0,0,0,0}, vi[8]={0,0,0,0,0,0,0,0};
    for (int h = 0; h < HH; ++h) {
        float2 u = us[h][cl], v = vs[h][cl];
        #pragma unroll
        for (int k = 0; k < 8; ++k) {
            int hp = k*16 + hg;
            float2 t = rt[(h*hp) & 127];      // e^{-i th}: (c, s) -> z*(c - i s)
            ur[k] += u.x*t.x + u.y*t.y;  ui[k] += u.y*t.x - u.x*t.y;
            vr[k] += v.x*t.x + v.y*t.y;  vi[k] += v.y*t.x - v.x*t.y;
        }
    }
    #pragma unroll
    for (int k = 0; k < 8; ++k) {
        int hp = k*16 + hg;
        aout[(size_t)((0*HH + hp)*WKEPT + wp)*CC + c0 + cl] = ur[k] + ui[k];
        aout[(size_t)((1*HH + hp)*WKEPT + wp)*CC + c0 + cl] = vr[k] + vi[k];
    }
}

// ---------------------------------------------------------------------------
// P5: H-axis 128-pt DFT + B butterfly on REAL s -> complex. Same shape as P3.
// ---------------------------------------------------------------------------
__global__ __launch_bounds__(256) void k_hb_s2c(
    const float* __restrict__ sreal, float2* __restrict__ out)
{
    const int tid = threadIdx.x;
    const int wp = blockIdx.y;
    const int c0 = blockIdx.x * CT3;
    __shared__ float us[HH][CT3];
    __shared__ float vs[HH][CT3];
    __shared__ float2 rt[HH];
    if (tid < HH) { float sn, cse; sincosf(TWOPI*(float)tid/128.f, &sn, &cse); rt[tid] = make_float2(cse, sn); }
    for (int idx = tid; idx < HH*CT3; idx += 256) {
        int h = idx / CT3, cl = idx - (idx / CT3)*CT3;
        float z0 = sreal[(size_t)((0*HH + h)*WKEPT + wp)*CC + c0 + cl];
        float z1 = sreal[(size_t)((1*HH + h)*WKEPT + wp)*CC + c0 + cl];
        us[h][cl] = z0 + z1;
        vs[h][cl] = z0 - z1;
    }
    __syncthreads();
    const int cl = tid & 15, hg = tid >> 4;
    float ur[8]={0,0,0,0,0,0,0,0}, ui[8]={0,0,0,0,0,0,0,0};
    float vr[8]={0,0,0,0,0,0,0,0}, vi[8]={0,0,0,0,0,0,0,0};
    for (int h = 0; h < HH; ++h) {
        float u = us[h][cl], v = vs[h][cl];
        #pragma unroll
        for (int k = 0; k < 8; ++k) {
            int hp = k*16 + hg;
            float2 t = rt[(h*hp) & 127];
            ur[k] += u*t.x;  ui[k] -= u*t.y;
            vr[k] += v*t.x;  vi[k] -= v*t.y;
        }
    }
    #pragma unroll
    for (int k = 0; k < 8; ++k) {
        int hp = k*16 + hg;
        out[(size_t)((0*HH + hp)*WKEPT + wp)*CC + c0 + cl] = make_float2(ur[k], ui[k]);
        out[(size_t)((1*HH + hp)*WKEPT + wp)*CC + c0 + cl] = make_float2(vr[k], vi[k]);
    }
}

// ---------------------------------------------------------------------------
// P4a: layer1. o1k = relu(a@w1p + an@w1m + b1[0]), o1nk = relu(an@w1p + a@w1m + b1[1])
// an gathered from flipped x. grid (260 ptiles of 64, 8 n), 256 thr.
// Tiles in LDS (i-major, stride 67); weights streamed from L2 (wave-broadcast).
// ---------------------------------------------------------------------------
__global__ __launch_bounds__(256) void k_mlp1(
    const float* __restrict__ a, const float* __restrict__ x,
    const float* __restrict__ W1P, const float* __restrict__ W1M,
    const float* __restrict__ b1,
    float* __restrict__ o1k, float* __restrict__ o1nk)
{
    const int tid = threadIdx.x;
    const int n = blockIdx.y;
    const int P0 = blockIdx.x * 64;
    __shared__ float at_s[BS*67];    // [i][p], 25.2 KB
    __shared__ float ant_s[BS*67];

    for (int idx = tid; idx < 64*BS; idx += 256) {
        int p = idx / BS, i = idx - p*BS;
        int P = P0 + p;
        at_s[i*67 + p] = a[(size_t)P*CC + n*BS + i];
        int b = P / (HH*WKEPT);
        int rem = P - b*(HH*WKEPT);
        int h = rem / WKEPT;
        int wq = rem - h*WKEPT;
        int hh2 = (HH - h) & (HH-1);
        int ww2 = (WW - wq) & (WW-1);
        ant_s[i*67 + p] = x[(size_t)((b*HH + hh2)*WW + ww2)*CC + n*BS + i];
    }
    __syncthreads();

    const int p = tid & 63, og = tid >> 6, ob = og*24;
    float ak[24], ank[24];
    #pragma unroll
    for (int j = 0; j < 24; ++j) { ak[j] = 0.f; ank[j] = 0.f; }
    const float* wpb = W1P + n*BS*BS;
    const float* wmb = W1M + n*BS*BS;
    for (int i = 0; i < BS; ++i) {
        float av = at_s[i*67 + p], anv = ant_s[i*67 + p];
        const float4* p4 = (const float4*)(wpb + i*BS + ob);
        const float4* m4 = (const float4*)(wmb + i*BS + ob);
        #pragma unroll
        for (int jj = 0; jj < 6; ++jj) {
            float4 qp = p4[jj], qm = m4[jj];
            ak [4*jj+0] += av*qp.x + anv*qm.x;  ank[4*jj+0] += anv*qp.x + av*qm.x;
            ak [4*jj+1] += av*qp.y + anv*qm.y;  ank[4*jj+1] += anv*qp.y + av*qm.y;
            ak [4*jj+2] += av*qp.z + anv*qm.z;  ank[4*jj+2] += anv*qp.z + av*qm.z;
            ak [4*jj+3] += av*qp.w + anv*qm.w;  ank[4*jj+3] += anv*qp.w + av*qm.w;
        }
    }
    __syncthreads();
    #pragma unroll
    for (int j = 0; j < 24; ++j) {
        int o = ob + j;
        at_s [p*97 + o] = fmaxf(ak[j]  + b1[(0*NB + n)*BS + o], 0.f);
        ant_s[p*97 + o] = fmaxf(ank[j] + b1[(1*NB + n)*BS + o], 0.f);
    }
    __syncthreads();
    for (int idx = tid; idx < 64*BS; idx += 256) {
        int p2 = idx / BS, o = idx - p2*BS;
        size_t g = (size_t)(P0 + p2)*CC + n*BS + o;
        o1k[g]  = at_s[p2*97 + o];
        o1nk[g] = ant_s[p2*97 + o];
    }
}

// ---------------------------------------------------------------------------
// P4b: collapsed layer2 + soft-threshold.  s = st(o1k@WK + o1nk@WNK + BEFF)
// ---------------------------------------------------------------------------
__global__ __launch_bounds__(256) void k_mlp2(
    const float* __restrict__ o1k, const float* __restrict__ o1nk,
    const float* __restrict__ WKm, const float* __restrict__ WNK,
    const float* __restrict__ BEFF, float* __restrict__ sout)
{
    const int tid = threadIdx.x;
    const int n = blockIdx.y;
    const int P0 = blockIdx.x * 64;
    __shared__ float tk[BS*67];
    __shared__ float tn[BS*67];
    for (int idx = tid; idx < 64*BS; idx += 256) {
        int p = idx / BS, i = idx - p*BS;
        size_t g = (size_t)(P0 + p)*CC + n*BS + i;
        tk[i*67 + p] = o1k[g];
        tn[i*67 + p] = o1nk[g];
    }
    __syncthreads();
    const int p = tid & 63, og = tid >> 6, ob = og*24;
    float acc[24];
    #pragma unroll
    for (int j = 0; j < 24; ++j) acc[j] = 0.f;
    const float* wkb = WKm + n*BS*BS;
    const float* wnb = WNK + n*BS*BS;
    for (int i = 0; i < BS; ++i) {
        float vk = tk[i*67 + p], vn = tn[i*67 + p];
        const float4* k4 = (const float4*)(wkb + i*BS + ob);
        const float4* n4 = (const float4*)(wnb + i*BS + ob);
        #pragma unroll
        for (int jj = 0; jj < 6; ++jj) {
            float4 qk = k4[jj], qn = n4[jj];
            acc[4*jj+0] += vk*qk.x + vn*qn.x;
            acc[4*jj+1] += vk*qk.y + vn*qn.y;
            acc[4*jj+2] += vk*qk.z + vn*qn.z;
            acc[4*jj+3] += vk*qk.w + vn*qn.w;
        }
    }
    __syncthreads();
    #pragma unroll
    for (int j = 0; j < 24; ++j) {
        int o = ob + j;
        float v = acc[j] + BEFF[n*BS + o];
        float av = fabsf(v) - 0.01f;
        tk[p*97 + o] = (av > 0.f) ? copysignf(av, v) : 0.f;
    }
    __syncthreads();
    for (int idx = tid; idx < 64*BS; idx += 256) {
        int p2 = idx / BS, o = idx - p2*BS;
        sout[(size_t)(P0 + p2)*CC + n*BS + o] = tk[p2*97 + o];
    }
}

// ---------------------------------------------------------------------------
// P7: inverse W expansion (65 -> 256), Re+Im, /Ntot, + bias x.
// grid (96 = 3 ctiles * 32 wgroups, 128 h, 2 b), 256 thr.
// contribution per w' = Ar*(cos-sin) + Ai*(cos+sin), theta = 2pi*w*w'/256.
// ---------------------------------------------------------------------------
__global__ __launch_bounds__(256) void k_p7(
    const float2* __restrict__ A, const float* __restrict__ x,
    float* __restrict__ out)
{
    const int tid = threadIdx.x;
    const int ct = blockIdx.x % 3;
    const int wg = blockIdx.x / 3;        // 0..31
    const int h = blockIdx.y, b = blockIdx.z;
    const int c = ct*256 + tid;
    __shared__ float cm[WKEPT][8];
    __shared__ float cp[WKEPT][8];
    for (int idx = tid; idx < WKEPT*8; idx += 256) {
        int wq = idx >> 3, j = idx & 7;
        int w = wg*8 + j;
        int ai = (w * wq) & 255;
        float sn, cse; sincosf(TWOPI * (float)ai / 256.f, &sn, &cse);
        cm[wq][j] = cse - sn;
        cp[wq][j] = cse + sn;
    }
    __syncthreads();
    float acc[8] = {0,0,0,0,0,0,0,0};
    const float2* Ab = A + (size_t)((b*HH + h)*WKEPT)*CC + c;
    for (int wq = 0; wq < WKEPT; ++wq) {
        float2 v = Ab[(size_t)wq*CC];
        const float4* m4 = (const float4*)(&cm[wq][0]);
        const float4* p4 = (const float4*)(&cp[wq][0]);
        #pragma unroll
        for (int jj = 0; jj < 2; ++jj) {
            float4 qm = m4[jj], qp = p4[jj];
            acc[4*jj+0] += v.x*qm.x + v.y*qp.x;
            acc[4*jj+1] += v.x*qm.y + v.y*qp.y;
            acc[4*jj+2] += v.x*qm.z + v.y*qp.z;
            acc[4*jj+3] += v.x*qm.w + v.y*qp.w;
        }
    }
    const float scale = 1.0f / 50331648.0f;
    size_t base = (size_t)(b*HH + h)*WW*CC + c;
    #pragma unroll
    for (int j = 0; j < 8; ++j) {
        int w = wg*8 + j;
        size_t g = base + (size_t)w*CC;
        out[g] = fmaf(acc[j], scale, x[g]);
    }
}

// ---------------------------------------------------------------------------
// Launch. ws layout (floats):
//   [0 : 25,559,040)           complex buffer A (16640*768 float2)
//        first half doubles as a_real, second half as s_real
//   [25,559,040 ...)           W1P, W1M, WK, WNK (each 73728), BEFF (768)
// needs ~103.4 MB of d_ws. d_out doubles as complex buffer B / o1 scratch.
// ---------------------------------------------------------------------------
extern "C" void kernel_launch(void* const* d_in, const int* in_sizes, int n_in,
                              void* d_out, int out_size, void* d_ws, size_t ws_size,
                              hipStream_t stream)
{
    (void)in_sizes; (void)n_in; (void)out_size; (void)ws_size;
    const float* x  = (const float*)d_in[0];
    const float* w1 = (const float*)d_in[1];
    const float* b1 = (const float*)d_in[2];
    const float* w2 = (const float*)d_in[3];
    const float* b2 = (const float*)d_in[4];

    float*  ws     = (float*)d_ws;
    float2* Abuf   = (float2*)d_ws;                     // 16640*768 float2
    float*  a_real = ws;                                // 12,779,520 floats
    float*  s_real = ws + (size_t)NPTS*CC;              // 12,779,520 floats
    float*  W1P    = ws + 2*(size_t)NPTS*CC;
    float*  W1M    = W1P + NB*BS*BS;
    float*  WKm    = W1M + NB*BS*BS;
    float*  WNK    = WKm + NB*BS*BS;
    float*  BEFF   = WNK + NB*BS*BS;

    float2* Bc   = (float2*)d_out;                      // complex scratch
    float*  o1k  = (float*)d_out;                       // layer1 scratch
    float*  o1nk = (float*)d_out + (size_t)NPTS*CC;
    float*  outf = (float*)d_out;

    k_weights<<<dim3(NB), dim3(256), 0, stream>>>(w1, w2, b2, W1P, W1M, WKm, WNK, BEFF);
    k_p1     <<<dim3(27, HH, BB), dim3(256), 0, stream>>>(x, Abuf);
    k_cdft   <<<dim3(WKEPT, HH, BB), dim3(256), 0, stream>>>(Abuf, Bc);
    k_hb_c2a <<<dim3(48, WKEPT), dim3(256), 0, stream>>>(Bc, a_real);
    k_mlp1   <<<dim3(260, NB), dim3(256), 0, stream>>>(a_real, x, W1P, W1M, b1, o1k, o1nk);
    k_mlp2   <<<dim3(260, NB), dim3(256), 0, stream>>>(o1k, o1nk, WKm, WNK, BEFF, s_real);
    k_hb_s2c <<<dim3(48, WKEPT), dim3(256), 0, stream>>>(s_real, Bc);
    k_cdft   <<<dim3(WKEPT, HH, BB), dim3(256), 0, stream>>>(Bc, Abuf);
    k_p7     <<<dim3(96, HH, BB), dim3(256), 0, stream>>>(Abuf, x, outf);
}

// Round 2
// 2404.062 us; speedup vs baseline: 1.4403x; 1.4403x over previous
//
#include <hip/hip_runtime.h>

#define BB 2
#define HH 128
#define WW 256
#define CC 768
#define NB 8
#define BS 96
#define WKEPT 65
#define NPTS (BB*HH*WKEPT)        // 16640 kept (b,h,w') points
#define NTOT ((size_t)BB*HH*WW*CC) // 50331648
#define TWOPI 6.283185307179586f

// ---------------------------------------------------------------------------
// K0: precombine weights.
// w1p=0.5(w1[0]+w1[1]), w1m=0.5(w1[0]-w1[1])
// layer2 collapsed:  s = o1k*WK + o1nk*WNK + BEFF
//   WK  = w2p + w2p@w2m
//   WNK = w2p + w2m + w2m@w2m
//   BEFF= b2[0] + b2[1] + b2[0]@w2m
// ---------------------------------------------------------------------------
__global__ __launch_bounds__(256) void k_weights(
    const float* __restrict__ w1, const float* __restrict__ w2,
    const float* __restrict__ b2,
    float* __restrict__ W1P, float* __restrict__ W1M,
    float* __restrict__ WKm, float* __restrict__ WNK, float* __restrict__ BEFF)
{
    const int n = blockIdx.x;
    const int tid = threadIdx.x;
    __shared__ float m_s[BS*BS];   // w2m, 36.9 KB

    const float* w2a = w2 + (size_t)(0*NB + n)*BS*BS;
    const float* w2b = w2 + (size_t)(1*NB + n)*BS*BS;
    for (int idx = tid; idx < BS*BS; idx += 256)
        m_s[idx] = 0.5f*(w2a[idx] - w2b[idx]);

    const float* w1a = w1 + (size_t)(0*NB + n)*BS*BS;
    const float* w1b = w1 + (size_t)(1*NB + n)*BS*BS;
    for (int idx = tid; idx < BS*BS; idx += 256) {
        float t0 = w1a[idx], t1 = w1b[idx];
        W1P[n*BS*BS + idx] = 0.5f*(t0 + t1);
        W1M[n*BS*BS + idx] = 0.5f*(t0 - t1);
    }
    __syncthreads();

    for (int idx = tid; idx < BS*BS; idx += 256) {
        int i = idx / BS, o = idx - i*BS;
        float p_io = 0.5f*(w2a[idx] + w2b[idx]);
        float m_io = m_s[idx];
        float accK = 0.f, accN = 0.f;
        for (int j = 0; j < BS; ++j) {
            float p_ij = 0.5f*(w2a[i*BS + j] + w2b[i*BS + j]);
            float mjo  = m_s[j*BS + o];
            accK += p_ij * mjo;
            accN += m_s[i*BS + j] * mjo;
        }
        WKm[n*BS*BS + idx] = p_io + accK;
        WNK[n*BS*BS + idx] = p_io + m_io + accN;
    }
    if (tid < BS) {
        const float* b2a = b2 + (0*NB + n)*BS;
        const float* b2b = b2 + (1*NB + n)*BS;
        float acc = b2a[tid] + b2b[tid];
        for (int j = 0; j < BS; ++j) acc += b2a[j] * m_s[j*BS + tid];
        BEFF[n*BS + tid] = acc;
    }
}

// ---------------------------------------------------------------------------
// P1: forward W-axis pruned DFT (256 -> 65 outputs), real input.
// grid (27 = 3 ctiles * 9 wgroups, 128 h, 2 b), 256 thr. out[b][h][w'][c] cplx
// ---------------------------------------------------------------------------
__global__ __launch_bounds__(256) void k_p1(
    const float* __restrict__ x, float2* __restrict__ out)
{
    const int tid = threadIdx.x;
    const int ct = blockIdx.x % 3;
    const int wg = blockIdx.x / 3;        // 0..8
    const int h = blockIdx.y, b = blockIdx.z;
    const int c = ct*256 + tid;
    const int wpb = wg*8;

    __shared__ float2 tw[256][8];         // 16 KB: (cos,sin) of 2*pi*w*(wpb+j)/256
    for (int idx = tid; idx < 2048; idx += 256) {
        int w = idx >> 3, j = idx & 7;
        int ai = (w * (wpb + j)) & 255;
        float sn, cs; sincosf(TWOPI * (float)ai / 256.0f, &sn, &cs);
        tw[w][j] = make_float2(cs, sn);
    }
    __syncthreads();

    float re[8] = {0,0,0,0,0,0,0,0}, im[8] = {0,0,0,0,0,0,0,0};
    const float* xrow = x + (size_t)(b*HH + h) * WW * CC + c;
    for (int w = 0; w < 256; ++w) {
        float xv = xrow[(size_t)w * CC];
        const float4* t4 = (const float4*)(&tw[w][0]);
        #pragma unroll
        for (int jj = 0; jj < 4; ++jj) {
            float4 q = t4[jj];            // (c0,s0,c1,s1)
            re[2*jj]   += xv * q.x;  im[2*jj]   -= xv * q.y;
            re[2*jj+1] += xv * q.z;  im[2*jj+1] -= xv * q.w;
        }
    }
    #pragma unroll
    for (int j = 0; j < 8; ++j) {
        int wp = wpb + j;
        if (wp < WKEPT)
            out[(size_t)((b*HH + h)*WKEPT + wp) * CC + c] = make_float2(re[j], im[j]);
    }
}

// ---------------------------------------------------------------------------
// P2/P6: C-axis 768-pt FFT per line (batched). 768 = 3 x 256:
// three 256-pt radix-2 Stockham FFTs (8 stages, LDS ping-pong, twiddle table)
// + twiddled radix-3 combine. 4 lines per block, 256 thr.
// grid (16640/4). layout [line][c] cplx, in-place-safe (separate in/out).
// ---------------------------------------------------------------------------
#define LPB 4
__global__ __launch_bounds__(256) void k_cfft(
    const float2* __restrict__ in, float2* __restrict__ out)
{
    __shared__ float2 tw[CC];          // 6 KB: e^{-2pi i t/768}
    __shared__ float2 bufA[LPB*CC];    // 24.6 KB
    __shared__ float2 bufB[LPB*CC];    // 24.6 KB
    const int tid = threadIdx.x;
    const size_t line0 = (size_t)blockIdx.x * LPB;

    for (int t = tid; t < CC; t += 256) {
        float sn, cs; sincosf(TWOPI * (float)t / 768.0f, &sn, &cs);
        tw[t] = make_float2(cs, -sn);
    }
    // load + deinterleave: bufA[l*768 + j*256 + m] = in[line0+l][3m+j]
    for (int idx = tid; idx < LPB*CC; idx += 256) {
        int l = idx / CC, c = idx - l*CC;
        int m = c / 3, j = c - 3*m;
        bufA[l*CC + j*256 + m] = in[(line0 + l)*CC + c];
    }
    __syncthreads();

    float2* src = bufA;
    float2* dst = bufB;
    // 8 Stockham radix-2 stages; stage st: s=2^st, h=128>>st, n=256>>st
    #pragma unroll
    for (int st = 0; st < 8; ++st) {
        const int s = 1 << st;
        const int h = 128 >> st;
        for (int item = tid; item < LPB*3*128; item += 256) {
            int sub = item >> 7;           // l*3 + j
            int t   = item & 127;
            int q = t & (s - 1);
            int p = t >> st;
            float2 a = src[sub*256 + q + s*p];
            float2 b = src[sub*256 + q + s*(p + h)];
            float2 w = tw[p * (3 << st)];  // e^{-2pi i p / (256>>st)}
            float dx = a.x - b.x, dy = a.y - b.y;
            dst[sub*256 + q + s*(2*p)]     = make_float2(a.x + b.x, a.y + b.y);
            dst[sub*256 + q + s*(2*p + 1)] = make_float2(dx*w.x - dy*w.y, dx*w.y + dy*w.x);
        }
        __syncthreads();
        float2* tmp = src; src = dst; dst = tmp;
    }
    // after 8 stages src == bufA; src[(l*3+j)*256 + r] = S_j[r]
    // combine: X[cp] = S0[r] + w1*S1[r] + w2*S2[r], cp = q*256+r,
    //          w1 = tw[cp], w2 = tw[(2cp)%768]
    for (int idx = tid; idx < LPB*CC; idx += 256) {
        int l = idx / CC, cp = idx - l*CC;
        int r = cp & 255;
        float2 S0 = src[(l*3 + 0)*256 + r];
        float2 S1 = src[(l*3 + 1)*256 + r];
        float2 S2 = src[(l*3 + 2)*256 + r];
        float2 w1 = tw[cp];
        int i2 = 2*cp; if (i2 >= CC) i2 -= CC;
        float2 w2 = tw[i2];
        float fr = S0.x + w1.x*S1.x - w1.y*S1.y + w2.x*S2.x - w2.y*S2.y;
        float fi = S0.y + w1.x*S1.y + w1.y*S1.x + w2.x*S2.y + w2.y*S2.x;
        out[(line0 + l)*CC + cp] = make_float2(fr, fi);
    }
}

// ---------------------------------------------------------------------------
// P3: H-axis 128-pt DFT + B-axis butterfly on complex input, then a=Re+Im.
// grid (48 ctiles of 16, 65 w'), 256 thr.
// ---------------------------------------------------------------------------
#define CT3 16
__global__ __launch_bounds__(256) void k_hb_c2a(
    const float2* __restrict__ in, float* __restrict__ aout)
{
    const int tid = threadIdx.x;
    const int wp = blockIdx.y;
    const int c0 = blockIdx.x * CT3;
    __shared__ float2 us[HH][CT3];  // 16 KB
    __shared__ float2 vs[HH][CT3];  // 16 KB
    __shared__ float2 rt[HH];       // (cos,sin) of 2*pi*j/128
    if (tid < HH) { float sn, cse; sincosf(TWOPI*(float)tid/128.f, &sn, &cse); rt[tid] = make_float2(cse, sn); }
    for (int idx = tid; idx < HH*CT3; idx += 256) {
        int h = idx / CT3, cl = idx - (idx / CT3)*CT3;
        float2 z0 = in[(size_t)((0*HH + h)*WKEPT + wp)*CC + c0 + cl];
        float2 z1 = in[(size_t)((1*HH + h)*WKEPT + wp)*CC + c0 + cl];
        us[h][cl] = make_float2(z0.x+z1.x, z0.y+z1.y);
        vs[h][cl] = make_float2(z0.x-z1.x, z0.y-z1.y);
    }
    __syncthreads();
    const int cl = tid & 15, hg = tid >> 4;   // hg 0..15, h' = k*16+hg
    float ur[8]={0,0,0,0,0,0,0,0}, ui[8]={0,0,0,0,0,0,0,0};
    float vr[8]={0,0,0,0,0,0,0,0}, vi[8]={0,0,0,0,0,0,0,0};
    for (int h = 0; h < HH; ++h) {
        float2 u = us[h][cl], v = vs[h][cl];
        #pragma unroll
        for (int k = 0; k < 8; ++k) {
            int hp = k*16 + hg;
            float2 t = rt[(h*hp) & 127];      // e^{-i th}: (c, s) -> z*(c - i s)
            ur[k] += u.x*t.x + u.y*t.y;  ui[k] += u.y*t.x - u.x*t.y;
            vr[k] += v.x*t.x + v.y*t.y;  vi[k] += v.y*t.x - v.x*t.y;
        }
    }
    #pragma unroll
    for (int k = 0; k < 8; ++k) {
        int hp = k*16 + hg;
        aout[(size_t)((0*HH + hp)*WKEPT + wp)*CC + c0 + cl] = ur[k] + ui[k];
        aout[(size_t)((1*HH + hp)*WKEPT + wp)*CC + c0 + cl] = vr[k] + vi[k];
    }
}

// ---------------------------------------------------------------------------
// P5: H-axis 128-pt DFT + B butterfly on REAL s -> complex. Same shape as P3.
// ---------------------------------------------------------------------------
__global__ __launch_bounds__(256) void k_hb_s2c(
    const float* __restrict__ sreal, float2* __restrict__ out)
{
    const int tid = threadIdx.x;
    const int wp = blockIdx.y;
    const int c0 = blockIdx.x * CT3;
    __shared__ float us[HH][CT3];
    __shared__ float vs[HH][CT3];
    __shared__ float2 rt[HH];
    if (tid < HH) { float sn, cse; sincosf(TWOPI*(float)tid/128.f, &sn, &cse); rt[tid] = make_float2(cse, sn); }
    for (int idx = tid; idx < HH*CT3; idx += 256) {
        int h = idx / CT3, cl = idx - (idx / CT3)*CT3;
        float z0 = sreal[(size_t)((0*HH + h)*WKEPT + wp)*CC + c0 + cl];
        float z1 = sreal[(size_t)((1*HH + h)*WKEPT + wp)*CC + c0 + cl];
        us[h][cl] = z0 + z1;
        vs[h][cl] = z0 - z1;
    }
    __syncthreads();
    const int cl = tid & 15, hg = tid >> 4;
    float ur[8]={0,0,0,0,0,0,0,0}, ui[8]={0,0,0,0,0,0,0,0};
    float vr[8]={0,0,0,0,0,0,0,0}, vi[8]={0,0,0,0,0,0,0,0};
    for (int h = 0; h < HH; ++h) {
        float u = us[h][cl], v = vs[h][cl];
        #pragma unroll
        for (int k = 0; k < 8; ++k) {
            int hp = k*16 + hg;
            float2 t = rt[(h*hp) & 127];
            ur[k] += u*t.x;  ui[k] -= u*t.y;
            vr[k] += v*t.x;  vi[k] -= v*t.y;
        }
    }
    #pragma unroll
    for (int k = 0; k < 8; ++k) {
        int hp = k*16 + hg;
        out[(size_t)((0*HH + hp)*WKEPT + wp)*CC + c0 + cl] = make_float2(ur[k], ui[k]);
        out[(size_t)((1*HH + hp)*WKEPT + wp)*CC + c0 + cl] = make_float2(vr[k], vi[k]);
    }
}

// ---------------------------------------------------------------------------
// P4a: layer1. o1k = relu(a@w1p + an@w1m + b1[0]), o1nk = relu(an@w1p + a@w1m + b1[1])
// an gathered from flipped x. grid (260 ptiles of 64, 8 n), 256 thr.
// ---------------------------------------------------------------------------
__global__ __launch_bounds__(256) void k_mlp1(
    const float* __restrict__ a, const float* __restrict__ x,
    const float* __restrict__ W1P, const float* __restrict__ W1M,
    const float* __restrict__ b1,
    float* __restrict__ o1k, float* __restrict__ o1nk)
{
    const int tid = threadIdx.x;
    const int n = blockIdx.y;
    const int P0 = blockIdx.x * 64;
    __shared__ float at_s[BS*67];    // [i][p], 25.2 KB
    __shared__ float ant_s[BS*67];

    for (int idx = tid; idx < 64*BS; idx += 256) {
        int p = idx / BS, i = idx - p*BS;
        int P = P0 + p;
        at_s[i*67 + p] = a[(size_t)P*CC + n*BS + i];
        int b = P / (HH*WKEPT);
        int rem = P - b*(HH*WKEPT);
        int h = rem / WKEPT;
        int wq = rem - h*WKEPT;
        int hh2 = (HH - h) & (HH-1);
        int ww2 = (WW - wq) & (WW-1);
        ant_s[i*67 + p] = x[(size_t)((b*HH + hh2)*WW + ww2)*CC + n*BS + i];
    }
    __syncthreads();

    const int p = tid & 63, og = tid >> 6, ob = og*24;
    float ak[24], ank[24];
    #pragma unroll
    for (int j = 0; j < 24; ++j) { ak[j] = 0.f; ank[j] = 0.f; }
    const float* wpb = W1P + n*BS*BS;
    const float* wmb = W1M + n*BS*BS;
    for (int i = 0; i < BS; ++i) {
        float av = at_s[i*67 + p], anv = ant_s[i*67 + p];
        const float4* p4 = (const float4*)(wpb + i*BS + ob);
        const float4* m4 = (const float4*)(wmb + i*BS + ob);
        #pragma unroll
        for (int jj = 0; jj < 6; ++jj) {
            float4 qp = p4[jj], qm = m4[jj];
            ak [4*jj+0] += av*qp.x + anv*qm.x;  ank[4*jj+0] += anv*qp.x + av*qm.x;
            ak [4*jj+1] += av*qp.y + anv*qm.y;  ank[4*jj+1] += anv*qp.y + av*qm.y;
            ak [4*jj+2] += av*qp.z + anv*qm.z;  ank[4*jj+2] += anv*qp.z + av*qm.z;
            ak [4*jj+3] += av*qp.w + anv*qm.w;  ank[4*jj+3] += anv*qp.w + av*qm.w;
        }
    }
    __syncthreads();
    #pragma unroll
    for (int j = 0; j < 24; ++j) {
        int o = ob + j;
        at_s [p*97 + o] = fmaxf(ak[j]  + b1[(0*NB + n)*BS + o], 0.f);
        ant_s[p*97 + o] = fmaxf(ank[j] + b1[(1*NB + n)*BS + o], 0.f);
    }
    __syncthreads();
    for (int idx = tid; idx < 64*BS; idx += 256) {
        int p2 = idx / BS, o = idx - p2*BS;
        size_t g = (size_t)(P0 + p2)*CC + n*BS + o;
        o1k[g]  = at_s[p2*97 + o];
        o1nk[g] = ant_s[p2*97 + o];
    }
}

// ---------------------------------------------------------------------------
// P4b: collapsed layer2 + soft-threshold.  s = st(o1k@WK + o1nk@WNK + BEFF)
// ---------------------------------------------------------------------------
__global__ __launch_bounds__(256) void k_mlp2(
    const float* __restrict__ o1k, const float* __restrict__ o1nk,
    const float* __restrict__ WKm, const float* __restrict__ WNK,
    const float* __restrict__ BEFF, float* __restrict__ sout)
{
    const int tid = threadIdx.x;
    const int n = blockIdx.y;
    const int P0 = blockIdx.x * 64;
    __shared__ float tk[BS*67];
    __shared__ float tn[BS*67];
    for (int idx = tid; idx < 64*BS; idx += 256) {
        int p = idx / BS, i = idx - p*BS;
        size_t g = (size_t)(P0 + p)*CC + n*BS + i;
        tk[i*67 + p] = o1k[g];
        tn[i*67 + p] = o1nk[g];
    }
    __syncthreads();
    const int p = tid & 63, og = tid >> 6, ob = og*24;
    float acc[24];
    #pragma unroll
    for (int j = 0; j < 24; ++j) acc[j] = 0.f;
    const float* wkb = WKm + n*BS*BS;
    const float* wnb = WNK + n*BS*BS;
    for (int i = 0; i < BS; ++i) {
        float vk = tk[i*67 + p], vn = tn[i*67 + p];
        const float4* k4 = (const float4*)(wkb + i*BS + ob);
        const float4* n4 = (const float4*)(wnb + i*BS + ob);
        #pragma unroll
        for (int jj = 0; jj < 6; ++jj) {
            float4 qk = k4[jj], qn = n4[jj];
            acc[4*jj+0] += vk*qk.x + vn*qn.x;
            acc[4*jj+1] += vk*qk.y + vn*qn.y;
            acc[4*jj+2] += vk*qk.z + vn*qn.z;
            acc[4*jj+3] += vk*qk.w + vn*qn.w;
        }
    }
    __syncthreads();
    #pragma unroll
    for (int j = 0; j < 24; ++j) {
        int o = ob + j;
        float v = acc[j] + BEFF[n*BS + o];
        float av = fabsf(v) - 0.01f;
        tk[p*97 + o] = (av > 0.f) ? copysignf(av, v) : 0.f;
    }
    __syncthreads();
    for (int idx = tid; idx < 64*BS; idx += 256) {
        int p2 = idx / BS, o = idx - p2*BS;
        sout[(size_t)(P0 + p2)*CC + n*BS + o] = tk[p2*97 + o];
    }
}

// ---------------------------------------------------------------------------
// P7: inverse W expansion (65 -> 256), Re+Im, /Ntot, + bias x.
// grid (96 = 3 ctiles * 32 wgroups, 128 h, 2 b), 256 thr.
// ---------------------------------------------------------------------------
__global__ __launch_bounds__(256) void k_p7(
    const float2* __restrict__ A, const float* __restrict__ x,
    float* __restrict__ out)
{
    const int tid = threadIdx.x;
    const int ct = blockIdx.x % 3;
    const int wg = blockIdx.x / 3;        // 0..31
    const int h = blockIdx.y, b = blockIdx.z;
    const int c = ct*256 + tid;
    __shared__ float cm[WKEPT][8];
    __shared__ float cp[WKEPT][8];
    for (int idx = tid; idx < WKEPT*8; idx += 256) {
        int wq = idx >> 3, j = idx & 7;
        int w = wg*8 + j;
        int ai = (w * wq) & 255;
        float sn, cse; sincosf(TWOPI * (float)ai / 256.f, &sn, &cse);
        cm[wq][j] = cse - sn;
        cp[wq][j] = cse + sn;
    }
    __syncthreads();
    float acc[8] = {0,0,0,0,0,0,0,0};
    const float2* Ab = A + (size_t)((b*HH + h)*WKEPT)*CC + c;
    for (int wq = 0; wq < WKEPT; ++wq) {
        float2 v = Ab[(size_t)wq*CC];
        const float4* m4 = (const float4*)(&cm[wq][0]);
        const float4* p4 = (const float4*)(&cp[wq][0]);
        #pragma unroll
        for (int jj = 0; jj < 2; ++jj) {
            float4 qm = m4[jj], qp = p4[jj];
            acc[4*jj+0] += v.x*qm.x + v.y*qp.x;
            acc[4*jj+1] += v.x*qm.y + v.y*qp.y;
            acc[4*jj+2] += v.x*qm.z + v.y*qp.z;
            acc[4*jj+3] += v.x*qm.w + v.y*qp.w;
        }
    }
    const float scale = 1.0f / 50331648.0f;
    size_t base = (size_t)(b*HH + h)*WW*CC + c;
    #pragma unroll
    for (int j = 0; j < 8; ++j) {
        int w = wg*8 + j;
        size_t g = base + (size_t)w*CC;
        out[g] = fmaf(acc[j], scale, x[g]);
    }
}

// ---------------------------------------------------------------------------
// Launch. ws layout (floats):
//   [0 : 25,559,040)           complex buffer A (16640*768 float2)
//        first half doubles as a_real, second half as s_real
//   [25,559,040 ...)           W1P, W1M, WK, WNK (each 73728), BEFF (768)
// d_out doubles as complex buffer B / o1 scratch.
// ---------------------------------------------------------------------------
extern "C" void kernel_launch(void* const* d_in, const int* in_sizes, int n_in,
                              void* d_out, int out_size, void* d_ws, size_t ws_size,
                              hipStream_t stream)
{
    (void)in_sizes; (void)n_in; (void)out_size; (void)ws_size;
    const float* x  = (const float*)d_in[0];
    const float* w1 = (const float*)d_in[1];
    const float* b1 = (const float*)d_in[2];
    const float* w2 = (const float*)d_in[3];
    const float* b2 = (const float*)d_in[4];

    float*  ws     = (float*)d_ws;
    float2* Abuf   = (float2*)d_ws;                     // 16640*768 float2
    float*  a_real = ws;                                // 12,779,520 floats
    float*  s_real = ws + (size_t)NPTS*CC;              // 12,779,520 floats
    float*  W1P    = ws + 2*(size_t)NPTS*CC;
    float*  W1M    = W1P + NB*BS*BS;
    float*  WKm    = W1M + NB*BS*BS;
    float*  WNK    = WKm + NB*BS*BS;
    float*  BEFF   = WNK + NB*BS*BS;

    float2* Bc   = (float2*)d_out;                      // complex scratch
    float*  o1k  = (float*)d_out;                       // layer1 scratch
    float*  o1nk = (float*)d_out + (size_t)NPTS*CC;
    float*  outf = (float*)d_out;

    k_weights<<<dim3(NB), dim3(256), 0, stream>>>(w1, w2, b2, W1P, W1M, WKm, WNK, BEFF);
    k_p1     <<<dim3(27, HH, BB), dim3(256), 0, stream>>>(x, Abuf);
    k_cfft   <<<dim3(NPTS/LPB), dim3(256), 0, stream>>>(Abuf, Bc);
    k_hb_c2a <<<dim3(48, WKEPT), dim3(256), 0, stream>>>(Bc, a_real);
    k_mlp1   <<<dim3(260, NB), dim3(256), 0, stream>>>(a_real, x, W1P, W1M, b1, o1k, o1nk);
    k_mlp2   <<<dim3(260, NB), dim3(256), 0, stream>>>(o1k, o1nk, WKm, WNK, BEFF, s_real);
    k_hb_s2c <<<dim3(48, WKEPT), dim3(256), 0, stream>>>(s_real, Bc);
    k_cfft   <<<dim3(NPTS/LPB), dim3(256), 0, stream>>>(Bc, Abuf);
    k_p7     <<<dim3(96, HH, BB), dim3(256), 0, stream>>>(Abuf, x, outf);
}